// Round 20
// baseline (62.538 us; speedup 1.0000x reference)
//
#include <hip/hip_runtime.h>
#include <stdint.h>
#include <math.h>

#define B_SZ   2048
#define D_SZ   128
#define C_SZ   100000
#define S_SC   30.0f
#define C2LOG  43.2808512f                // 30*log2(e)
#define M2LOG  12.9837726f                // 9*log2(e)
#define A_QS   173.1234048f               // fp8 quant scale for f: C2LOG*4
#define B_QS   256.0f                     // fp8 quant scale for w
#define SCL_A  0x7D7D7D7Du                // e8m0 125 = 2^-2 (all 4 bytes)
#define SCL_B  0x77777777u                // e8m0 119 = 2^-8
#define SCHR_B 1065353216.0f              // 127<<23 as float (Schraudolph bias)
#define SCHR_S 8388608.0f                 // 2^23

// R9/R17/R18-proven gemm shape: BM=128 rows, 256 thr (4 waves 2x2);
// B subtile 64 cols x 128 fp8 = 8KB; LDS = 3 x 8KB rotation, 2-deep prefetch,
// counted vmcnt(2), one barrier per subtile; XCD-swizzled flat grid.
// R19 delta: epilogue exp2 -> Schraudolph bit-trick (fma+cvt, full-rate).
#define BM     128
#define BN     64
#define NSUB   16
#define CPB    (BN*NSUB)                  // 1024 cols per block
#define GRID_C ((C_SZ + CPB - 1)/CPB)     // 98
#define C_PAD  (GRID_C*CPB)               // 100352
#define N_RT   (B_SZ/BM)                  // 16 row tiles
#define NBLK   (GRID_C*N_RT)              // 1568 = 8 XCD x 196
// merge-time exact constant: 352 pad cols (2^0 each, Schraudolph(0)=1 exact)
// + one zero-primed accumulator epilogue per wave (+16/slot x 196 slots)
#define POST_SUB 3488.0f
#define NSLOT  (GRID_C*2)                 // 196 partial slots per row

typedef float f32x4 __attribute__((ext_vector_type(4)));
typedef int   i32x4 __attribute__((ext_vector_type(4)));
typedef int   i32x8 __attribute__((ext_vector_type(8)));
typedef unsigned char u8;

__device__ __forceinline__ void gload_lds16(const void* g, void* l) {
  __builtin_amdgcn_global_load_lds(
      (const __attribute__((address_space(1))) void*)g,
      (__attribute__((address_space(3))) void*)l, 16, 0, 0);
}

// ------- row L2-normalize (x qscale) -> fp8 e4m3; 2 rows/wave, 16B/lane -------
__global__ void rownorm_fp8v4_kernel(const float* __restrict__ in,
                                     u8* __restrict__ out, int rows,
                                     int valid_rows, float scale) {
  int lane = threadIdx.x & 63;
  int half = lane >> 5;
  int l31  = lane & 31;
  int row  = ((blockIdx.x * blockDim.x + threadIdx.x) >> 6) * 2 + half;
  if (row >= rows) return;
  unsigned* orow = (unsigned*)(out + (size_t)row * D_SZ);
  if (row >= valid_rows) {
    orow[l31] = 0u;
    return;
  }
  float4 v = ((const float4*)(in + (size_t)row * D_SZ))[l31];
  float ss = v.x * v.x + v.y * v.y + v.z * v.z + v.w * v.w;
  #pragma unroll
  for (int m = 1; m < 32; m <<= 1) ss += __shfl_xor(ss, m, 64);  // stays in half
  float rn = scale * rsqrtf(ss);
  int pk = __builtin_amdgcn_cvt_pk_fp8_f32(v.x * rn, v.y * rn, 0, false);
  pk     = __builtin_amdgcn_cvt_pk_fp8_f32(v.z * rn, v.w * rn, pk, true);
  orow[l31] = (unsigned)pk;                // 4 fp8 bytes per lane, coalesced
}

// ------- fused: normalize+quantize f rows AND exact fp32 label cos -------
__global__ void prep_f_kernel(const float* __restrict__ f,
                              const int* __restrict__ labels,
                              const float* __restrict__ w,
                              u8* __restrict__ fn, float* __restrict__ cosy) {
  int row  = (blockIdx.x * blockDim.x + threadIdx.x) >> 6;
  int lane = threadIdx.x & 63;
  if (row >= B_SZ) return;
  float2 fv = ((const float2*)(f + (size_t)row * D_SZ))[lane];
  float ff = fv.x * fv.x + fv.y * fv.y;
  #pragma unroll
  for (int m = 1; m < 64; m <<= 1) ff += __shfl_xor(ff, m, 64);
  float rn = A_QS / sqrtf(ff);
  int pk = __builtin_amdgcn_cvt_pk_fp8_f32(fv.x * rn, fv.y * rn, 0, false);
  ((unsigned short*)(fn + (size_t)row * D_SZ))[lane] = (unsigned short)(pk & 0xFFFF);

  int y = labels[row];
  float2 wv = ((const float2*)(w + (size_t)y * D_SZ))[lane];
  float d  = fv.x * wv.x + fv.y * wv.y;
  float ww = wv.x * wv.x + wv.y * wv.y;
  #pragma unroll
  for (int m = 1; m < 64; m <<= 1) {
    d  += __shfl_xor(d,  m, 64);
    ww += __shfl_xor(ww, m, 64);
  }
  if (lane == 0) {
    float c = d / (sqrtf(ff) * sqrtf(ww));
    c = fminf(1.0f, fmaxf(-1.0f, c));
    cosy[row] = c;
  }
}

// ---------------- fused MX-FP8 MFMA GEMM + softmax partials ----------------
// Flat grid 1568 with bijective XCD decode: xcd=bid&7, g=xcd*196+(bid>>3),
// cb=g>>4, rt=g&15 -> all 16 row-blocks of a cb land on ONE XCD.
// Epilogue: Schraudolph 2^x = int_as_float((int)(x*2^23 + 127*2^23)).
__global__ __launch_bounds__(256, 4) void gemm_partial_kernel(
    const u8* __restrict__ fn, const u8* __restrict__ wn,
    float* __restrict__ ps) {
  __shared__ __align__(16) u8 lds[3][BN * D_SZ];  // 3 x 8 KB

  const int tid  = threadIdx.x;
  const int lane = tid & 63;
  const int wid  = tid >> 6;
  const int wr   = wid >> 1, wc = wid & 1;
  const int bid  = blockIdx.x;
  const int g    = (bid & 7) * (NBLK / 8) + (bid >> 3);
  const int cb   = g >> 4;                  // 0..97
  const int r0   = (g & 15) * BM;
  const int hi   = lane >> 4;
  const int l15  = lane & 15;

  // ---- B staging pointers (advance by BN*D_SZ per subtile) ----
  const u8* bsrc[2];
  int wch2[2];
  #pragma unroll
  for (int it = 0; it < 2; ++it) {
    int idx = it * 256 + tid;               // 16B chunk id (0..511)
    int cl  = idx >> 3;                     // 0..63
    int s   = (idx & 7) ^ (cl & 7);
    bsrc[it] = wn + (size_t)(cb * CPB + cl) * D_SZ + s * 16;
    wch2[it] = it * 256 + (tid & ~63);
  }

  // ---- prologue: stage A (16KB) into buf1+buf2; B(0) -> buf0 concurrently ----
  u8* aflat = &lds[1][0];
  #pragma unroll
  for (int it = 0; it < 4; ++it) {
    int idx  = it * 256 + tid;              // 16B chunk id (0..1023)
    int r    = idx >> 3;
    int s    = (idx & 7) ^ (r & 7);         // pre-swizzled source slot
    int wch  = it * 256 + (tid & ~63);      // wave-uniform LDS chunk base
    gload_lds16(fn + (size_t)(r0 + r) * D_SZ + s * 16, aflat + wch * 16);
  }
  #pragma unroll
  for (int it = 0; it < 2; ++it)
    gload_lds16(bsrc[it], &lds[0][wch2[it] * 16]);

  asm volatile("s_waitcnt vmcnt(2)" ::: "memory");   // A done; B(0) in flight
  __builtin_amdgcn_s_barrier();

  // ---- A fragments -> registers (rows r0+wr*64+i*16+l15, K span hi*32..+32) ----
  i32x8 afrag[4];
  #pragma unroll
  for (int i = 0; i < 4; ++i) {
    int row = wr * 64 + i * 16 + l15;
    int s0  = (hi * 2)     ^ (row & 7);
    int s1  = (hi * 2 + 1) ^ (row & 7);
    i32x4 lo = *(const i32x4*)&aflat[row * D_SZ + s0 * 16];
    i32x4 h4 = *(const i32x4*)&aflat[row * D_SZ + s1 * 16];
    afrag[i] = __builtin_shufflevector(lo, h4, 0, 1, 2, 3, 4, 5, 6, 7);
  }
  asm volatile("s_waitcnt lgkmcnt(0)" ::: "memory");  // afrag in regs
  __builtin_amdgcn_s_barrier();                       // buf1/buf2 free for B

  // stage B(1) -> buf1   (outstanding now: B0:2 + B1:2 = 4)
  #pragma unroll
  for (int it = 0; it < 2; ++it) {
    bsrc[it] += BN * D_SZ;
    gload_lds16(bsrc[it], &lds[1][wch2[it] * 16]);
  }

  // hoisted bfrag slot offsets: col = wc*32 + j*16 + l15
  int boff[2][2];
  #pragma unroll
  for (int j = 0; j < 2; ++j) {
    int col = wc * 32 + j * 16 + l15;
    boff[j][0] = col * D_SZ + (((hi * 2)     ^ (col & 7)) * 16);
    boff[j][1] = col * D_SZ + (((hi * 2 + 1) ^ (col & 7)) * 16);
  }

  float sacc[4][4] = {};
  f32x4 acc0[4];
  f32x4 acc1[4] = {};            // zero-primed; consumed once (exact, POST_SUB)
  const f32x4 zero4 = {0.f, 0.f, 0.f, 0.f};

  #pragma unroll 1
  for (int sub = 0; sub < NSUB; ++sub) {
    if (sub < NSUB - 1) {
      asm volatile("s_waitcnt vmcnt(2)" ::: "memory");  // B(sub) landed
    } else {
      asm volatile("s_waitcnt vmcnt(0)" ::: "memory");  // last: drain
    }
    __builtin_amdgcn_s_barrier();    // all waves done with buf[(sub-1)%3]

    // prefetch B(sub+2) into buf[(sub+2)%3] (the buffer freed by the barrier)
    if (sub < NSUB - 2) {
      u8* dst = &lds[(sub + 2) % 3][0];
      #pragma unroll
      for (int it = 0; it < 2; ++it) {
        bsrc[it] += BN * D_SZ;
        gload_lds16(bsrc[it], dst + wch2[it] * 16);
      }
    }

    const u8* bbuf = &lds[sub % 3][0];

    // ---- j0: MFMA cluster, then epilogue of previous acc1 ----
    i32x8 b0;
    {
      i32x4 lo = *(const i32x4*)&bbuf[boff[0][0]];
      i32x4 h4 = *(const i32x4*)&bbuf[boff[0][1]];
      b0 = __builtin_shufflevector(lo, h4, 0, 1, 2, 3, 4, 5, 6, 7);
    }
    #pragma unroll
    for (int i = 0; i < 4; ++i)
      acc0[i] = __builtin_amdgcn_mfma_scale_f32_16x16x128_f8f6f4(
          afrag[i], b0, zero4, 0, 0, 0, SCL_A, 0, SCL_B);
    #pragma unroll
    for (int i = 0; i < 4; ++i) {
      f32x4 a4 = acc1[i];
      #pragma unroll
      for (int r = 0; r < 4; ++r) {
        int e = (int)__builtin_fmaf(a4[r], SCHR_S, SCHR_B);  // Schraudolph 2^x
        sacc[i][r] += __int_as_float(e);
      }
    }

    // ---- j1: MFMA cluster, then epilogue of acc0 ----
    i32x8 b1;
    {
      i32x4 lo = *(const i32x4*)&bbuf[boff[1][0]];
      i32x4 h4 = *(const i32x4*)&bbuf[boff[1][1]];
      b1 = __builtin_shufflevector(lo, h4, 0, 1, 2, 3, 4, 5, 6, 7);
    }
    #pragma unroll
    for (int i = 0; i < 4; ++i)
      acc1[i] = __builtin_amdgcn_mfma_scale_f32_16x16x128_f8f6f4(
          afrag[i], b1, zero4, 0, 0, 0, SCL_A, 0, SCL_B);
    #pragma unroll
    for (int i = 0; i < 4; ++i) {
      f32x4 a4 = acc0[i];
      #pragma unroll
      for (int r = 0; r < 4; ++r) {
        int e = (int)__builtin_fmaf(a4[r], SCHR_S, SCHR_B);
        sacc[i][r] += __int_as_float(e);
      }
    }
  }

  // ---- tail: epilogue of the last subtile's acc1 ----
  #pragma unroll
  for (int i = 0; i < 4; ++i) {
    f32x4 a4 = acc1[i];
    #pragma unroll
    for (int r = 0; r < 4; ++r) {
      int e = (int)__builtin_fmaf(a4[r], SCHR_S, SCHR_B);
      sacc[i][r] += __int_as_float(e);
    }
  }

  // ---- reduce across the 16 lanes sharing each row, write partials ----
  #pragma unroll
  for (int i = 0; i < 4; ++i)
    #pragma unroll
    for (int r = 0; r < 4; ++r) {
      float s = sacc[i][r];
      #pragma unroll
      for (int m = 1; m < 16; m <<= 1) s += __shfl_xor(s, m, 64);
      if (l15 == 0) {
        int rowg = r0 + wr * 64 + i * 16 + hi * 4 + r;
        ps[(size_t)rowg * NSLOT + cb * 2 + wc] = s;
      }
    }
}

// ---------------- merge partials -> per-row loss ----------------
__global__ void merge_kernel(const float* __restrict__ ps,
                             const float* __restrict__ cosy,
                             float* __restrict__ losses) {
  int row  = (blockIdx.x * blockDim.x + threadIdx.x) >> 6;
  int lane = threadIdx.x & 63;
  if (row >= B_SZ) return;
  float s = 0.0f;
  for (int k = lane; k < NSLOT; k += 64) s += ps[(size_t)row * NSLOT + k];
  #pragma unroll
  for (int m = 1; m < 64; m <<= 1) s += __shfl_xor(s, m, 64);
  if (lane == 0) {
    float cy  = cosy[row];
    float zy2 = C2LOG * cy;                 // log2-domain label logit
    s = s - POST_SUB - exp2f(zy2) + exp2f(zy2 - M2LOG);
    s = fmaxf(s, 1e-30f);
    float lse = logf(s);
    losses[row] = lse - 0.9f * (S_SC * cy - 9.0f);
  }
}

// ---------------- deterministic mean over B ----------------
__global__ void final_kernel(const float* __restrict__ losses, float* __restrict__ out) {
  __shared__ float red[256];
  int tid = threadIdx.x;
  float s = 0.0f;
  for (int k = tid; k < B_SZ; k += 256) s += losses[k];
  red[tid] = s;
  __syncthreads();
  for (int off = 128; off > 0; off >>= 1) {
    if (tid < off) red[tid] += red[tid + off];
    __syncthreads();
  }
  if (tid == 0) out[0] = red[0] / (float)B_SZ;
}

extern "C" void kernel_launch(void* const* d_in, const int* in_sizes, int n_in,
                              void* d_out, int out_size, void* d_ws, size_t ws_size,
                              hipStream_t stream) {
  const float* feat   = (const float*)d_in[0];
  const int*   labels = (const int*)d_in[1];
  const float* weight = (const float*)d_in[2];
  float* out = (float*)d_out;

  char* ws = (char*)d_ws;
  size_t off = 0;
  u8* wn = (u8*)(ws + off);          off += (size_t)C_PAD * D_SZ;      // 12.85 MB
  off = (off + 255) & ~(size_t)255;
  u8* fn = (u8*)(ws + off);          off += (size_t)B_SZ * D_SZ;       // 256 KB
  off = (off + 255) & ~(size_t)255;
  float* cosy = (float*)(ws + off);  off += (size_t)B_SZ * 4;
  off = (off + 255) & ~(size_t)255;
  float* ps = (float*)(ws + off);    off += (size_t)B_SZ * NSLOT * 4;  // 1.6 MB
  off = (off + 255) & ~(size_t)255;
  float* losses = (float*)(ws + off);

  rownorm_fp8v4_kernel<<<(C_PAD + 7) / 8, 256, 0, stream>>>(weight, wn, C_PAD, C_SZ, B_QS);
  prep_f_kernel<<<(B_SZ + 3) / 4, 256, 0, stream>>>(feat, labels, weight, fn, cosy);

  gemm_partial_kernel<<<NBLK, 256, 0, stream>>>(fn, wn, ps);

  merge_kernel<<<(B_SZ + 3) / 4, 256, 0, stream>>>(ps, cosy, losses);
  final_kernel<<<1, 256, 0, stream>>>(losses, out);
}